// Round 11
// baseline (414072.852 us; speedup 1.0000x reference)
//
#include <hip/hip_runtime.h>
#include <stdint.h>
#include <stddef.h>

typedef _Float16 f16;
typedef __attribute__((ext_vector_type(8))) _Float16 f16x8;
typedef __attribute__((ext_vector_type(4))) float f32x4;
typedef __attribute__((ext_vector_type(2))) double f64x2;

#define MFMA16(A,B,C) __builtin_amdgcn_mfma_f32_16x16x32_f16((A),(B),(C),0,0,0)

// B=128, T=1024, FEAT=256, HID=512, GATES=2048, K=768 (256 seq + 512 h)
// f64 recurrence (ref=np is f64-grade; step-error gain ~1e5).
// r9/r10 (passed, 39.7ms k2): VGPR=128 -> weights never VGPR-resident; the
// compiler remats f32 loads+cvt inside the bb loop => 16x weight re-stream
// from L2 (~3.1MB/WG/step ~ 24ms) is the wall. asm-pinning failed.
// This round: LOOP INTERCHANGE - outer over weight chunks (live range = one
// iteration, nothing to remat; each weight fetched from L2 once/step), inner
// over 16 bb into accA[16]/accB[16] (64 VGPR, statically indexed). Seq part
// hoisted before the barrier wait again. Everything else = r10 verbatim.

// ---------------- workspace byte offsets ----------------
#define WS_CZB   0            // f64[128][512][4]  = 2 MiB
#define WS_C0    2097152      // f64[128*512]      = 512 KiB
#define WS_HBUF  2621440      // f64[2][128][512]  = 1 MiB (parity, batch, unit)
#define WS_HLAST 3670016      // f64[128*512]      = 512 KiB
#define WS_WOF   4194304      // f16[256*512]      = 256 KiB
#define WS_CTR   4456448      // u32 counters (8 groups x 16 stride)

// JAX threefry2x32 (20 rounds), host+device
__host__ __device__ __forceinline__ void tf2x32(uint32_t k0,uint32_t k1,uint32_t x0,uint32_t x1,
                                                uint32_t* o0,uint32_t* o1){
  uint32_t ks2 = k0 ^ k1 ^ 0x1BD11BDAu;
  uint32_t a = x0 + k0, b = x1 + k1;
  #define TF_R(rot) { a += b; b = (b<<(rot))|(b>>(32-(rot))); b ^= a; }
  TF_R(13) TF_R(15) TF_R(26) TF_R(6)  a += k1;  b += ks2 + 1u;
  TF_R(17) TF_R(29) TF_R(16) TF_R(24) a += ks2; b += k0  + 2u;
  TF_R(13) TF_R(15) TF_R(26) TF_R(6)  a += k0;  b += k1  + 3u;
  TF_R(17) TF_R(29) TF_R(16) TF_R(24) a += k1;  b += ks2 + 4u;
  TF_R(13) TF_R(15) TF_R(26) TF_R(6)  a += ks2; b += k0  + 5u;
  #undef TF_R
  *o0 = a; *o1 = b;
}

// ---------------- K1a: embed h0/c0 + Czb (z-part + biases), all f64 ----------------
__global__ void k1a(const float* __restrict__ z, const float* __restrict__ Wemb,
                    const float* __restrict__ bemb, const float* __restrict__ Wih,
                    const float* __restrict__ bih, const float* __restrict__ bhh,
                    double* __restrict__ h0, double* __restrict__ c0,
                    double* __restrict__ czb)
{
  int gi = blockIdx.x*256 + threadIdx.x;       // 128*3072 threads
  int b = gi / 3072, j = gi % 3072;
  const float* zr = z + b*256;
  if (j < 1024) {
    const float* wr = Wemb + j*256;
    double s = (double)bemb[j];
    for (int k=0;k<256;k++) s += (double)zr[k] * (double)wr[k];
    double v = tanh(s);
    if (j < 512) h0[b*512 + j] = v;            // hbuf parity 0, [b][u]
    else         c0[b*512 + (j-512)] = v;
  } else {
    int g = j - 1024;
    const float* wr = Wih + g*512 + 256;       // z-columns of W_ih
    double s = (double)bih[g] + (double)bhh[g];
    for (int k=0;k<256;k++) s += (double)zr[k] * (double)wr[k];
    int q = g >> 9, u = g & 511;
    czb[(b*512 + u)*4 + q] = s;
  }
}

// ---------------- K1b: W_out -> f16 for the bulk projection ----------------
__global__ void k1b(const float* __restrict__ Wout, f16* __restrict__ wof)
{
  int e0 = (blockIdx.x*256 + threadIdx.x)*4;   // 128 blocks
  #pragma unroll
  for (int j=0;j<4;j++) wof[e0+j] = (f16)Wout[e0+j];
}

// ---------------- K2: persistent f64 LSTM, interchanged (stream-weights) ----------------
// 256 WGs x 512 thr (1/CU). WG = bG (16 batches) x nG (16 units = 64 gate rows).
// lane = kc*4 + rs; wave w owns units {2w, 2w+1}. Interchange: outer over
// weight chunks (f32x4 per row, used immediately, never resident), inner over
// all 16 bb into accA[16]/accB[16]. Seq part before the wait; ONE butterfly
// per bb after the h part. x/h in XOR-swizzled LDS; per-bG 32-WG barrier.
__global__ __launch_bounds__(512, 2) void k2t(
    const float* __restrict__ seq, const float* __restrict__ Wih,
    const float* __restrict__ Whh,
    const double* __restrict__ czbv, const double* __restrict__ c0v,
    double* __restrict__ hbuf, f16* __restrict__ hs, double* __restrict__ hlast,
    unsigned int* __restrict__ ctr)
{
  __shared__ double xl[4096];      // 32KB  x_t  [bb][256]
  __shared__ double hl[8192];      // 64KB  h_t  [bb][512]
  __shared__ double sc[1024];      // 8KB   gate sums [bb][q][ul]
  __shared__ double czl[1024];     // 8KB   biases, same layout

  const int tid = threadIdx.x;
  const int bid = blockIdx.x;
  const int bG = bid & 7, nG = bid >> 3;
  const int w = tid >> 6, lane = tid & 63;
  const int kc = lane >> 2, rs = lane & 3;
  const int XR = (kc & 7) << 4;                        // read-side swizzle const

  // physical gate rows for this lane's two units
  const int uA = nG*16 + 2*w;
  const size_t rA = (size_t)(rs*512 + uA);
  const size_t rB = rA + 1;

  const float* wiA = Wih + rA*512 + kc*16;   // seq weights, this lane's chunk
  const float* wiB = Wih + rB*512 + kc*16;
  const float* whA = Whh + rA*512 + kc*32;   // h weights, this lane's chunk
  const float* whB = Whh + rB*512 + kc*32;

  // ---- one-time: biases into LDS (czl[bb*64 + q*16 + ul]) ----
  for (int s = tid; s < 1024; s += 512) {
    int bb = s >> 6, q = (s >> 4) & 3, ul = s & 15;
    czl[s] = czbv[(size_t)((bG*16+bb)*512 + nG*16 + ul)*4 + q];
  }

  // elementwise ownership (tid < 256): cc in register for all 1024 steps
  double cc = 0.0;
  if (tid < 256) cc = c0v[(size_t)(bG*16 + (tid>>4))*512 + nG*16 + (tid&15)];

  // staging geometry
  const int lane5 = tid & 31;
  const int srow  = tid >> 5;        // 0..15 (batch row for staging)
  const int xchk  = lane5 >> 1;      // x: 128B chunk 0..15 (2 threads/chunk)
  const int xhalf = lane5 & 1;       // which 4-pair half
  const int xswz  = xchk & 7;
  const int hswz  = (lane5 >> 1) & 7;  // h: chunk = lane5, swz = (chunk>>1)&7

  unsigned int* mc = &ctr[bG*16];
  __syncthreads();

  for (int t = 0; t < 1024; ++t) {
    // -------- stage x_t: f32 -> f64, XOR-swizzled (8 elems/thread) --------
    {
      const float* xsrc = seq + (size_t)(bG*16 + srow)*262144 + (size_t)t*256 + lane5*8;
      f32x4 v0 = *(const f32x4*)xsrc;
      f32x4 v1 = *(const f32x4*)(xsrc + 4);
      char* wbase = (char*)xl + srow*2048 + xchk*128;
      f64x2 pr0 = {(double)v0.x, (double)v0.y};
      f64x2 pr1 = {(double)v0.z, (double)v0.w};
      f64x2 pr2 = {(double)v1.x, (double)v1.y};
      f64x2 pr3 = {(double)v1.z, (double)v1.w};
      *(f64x2*)(wbase + (((xhalf*4 + 0) ^ xswz) << 4)) = pr0;
      *(f64x2*)(wbase + (((xhalf*4 + 1) ^ xswz) << 4)) = pr1;
      *(f64x2*)(wbase + (((xhalf*4 + 2) ^ xswz) << 4)) = pr2;
      *(f64x2*)(wbase + (((xhalf*4 + 3) ^ xswz) << 4)) = pr3;
    }
    __syncthreads();

    // -------- accumulators (statically indexed; 64 VGPR) --------
    double accA[16], accB[16];
    #pragma unroll
    for (int bb=0;bb<16;++bb){ accA[bb]=0.; accB[bb]=0.; }

    // -------- seq part: outer weight chunk, inner bb (h-independent) --------
    #pragma unroll
    for (int j4 = 0; j4 < 4; ++j4) {
      f32x4 wa = *(const f32x4*)(wiA + j4*4);
      f32x4 wb = *(const f32x4*)(wiB + j4*4);
      double wA0=(double)wa.x, wA1=(double)wa.y, wA2=(double)wa.z, wA3=(double)wa.w;
      double wB0=(double)wb.x, wB1=(double)wb.y, wB2=(double)wb.z, wB3=(double)wb.w;
      const int o0 = ((2*j4)*16) ^ XR;
      const int o1 = ((2*j4+1)*16) ^ XR;
      #pragma unroll
      for (int bb=0;bb<16;++bb){
        const char* xb = (const char*)xl + bb*2048 + kc*128;
        f64x2 x0 = *(const f64x2*)(xb + o0);
        f64x2 x1 = *(const f64x2*)(xb + o1);
        accA[bb] += wA0*x0.x + wA1*x0.y + wA2*x1.x + wA3*x1.y;
        accB[bb] += wB0*x0.x + wB1*x0.y + wB2*x1.x + wB3*x1.y;
      }
    }

    // -------- wait: all 32 same-bG WGs published h_t --------
    if (t) {
      if (tid == 0) {
        unsigned tgt = 32u * (unsigned)t;
        while (__hip_atomic_load(mc, __ATOMIC_RELAXED, __HIP_MEMORY_SCOPE_AGENT) < tgt)
          __builtin_amdgcn_s_sleep(1);
        (void)__hip_atomic_load(mc, __ATOMIC_ACQUIRE, __HIP_MEMORY_SCOPE_AGENT);
      }
    }
    __syncthreads();

    // -------- stage h_t: global f64 -> LDS, XOR-swizzled (16 elems/thread) --------
    {
      const double* hsrc = hbuf + (size_t)(t & 1)*65536 + (size_t)(bG*16 + srow)*512 + lane5*16;
      char* wbase = (char*)hl + srow*4096 + lane5*128;
      #pragma unroll
      for (int g = 0; g < 8; ++g) {
        f64x2 hv = *(const f64x2*)(hsrc + 2*g);
        *(f64x2*)(wbase + ((g ^ hswz) << 4)) = hv;
      }
    }
    __syncthreads();

    // -------- h part: outer weight chunk, inner bb --------
    #pragma unroll
    for (int j4 = 0; j4 < 8; ++j4) {
      f32x4 wa = *(const f32x4*)(whA + j4*4);
      f32x4 wb = *(const f32x4*)(whB + j4*4);
      double wA0=(double)wa.x, wA1=(double)wa.y, wA2=(double)wa.z, wA3=(double)wa.w;
      double wB0=(double)wb.x, wB1=(double)wb.y, wB2=(double)wb.z, wB3=(double)wb.w;
      const int o0 = ((2*j4)*16) ^ XR;
      const int o1 = ((2*j4+1)*16) ^ XR;
      #pragma unroll
      for (int bb=0;bb<16;++bb){
        const char* hb2 = (const char*)hl + bb*4096 + kc*256;
        f64x2 h0 = *(const f64x2*)(hb2 + o0);
        f64x2 h1 = *(const f64x2*)(hb2 + o1);
        accA[bb] += wA0*h0.x + wA1*h0.y + wA2*h1.x + wA3*h1.y;
        accB[bb] += wB0*h0.x + wB1*h0.y + wB2*h1.x + wB3*h1.y;
      }
    }

    // -------- butterfly per bb (reduce over 16 kc lanes) --------
    #pragma unroll
    for (int bb=0;bb<16;++bb){
      double aA = accA[bb], aB = accB[bb];
      #pragma unroll
      for (int off = 4; off < 64; off <<= 1) {
        aA += __shfl_xor(aA, off, 64);
        aB += __shfl_xor(aB, off, 64);
      }
      if (kc == 0) sc[bb*64 + rs*16 + 2*w]     = aA;
      if (kc == 1) sc[bb*64 + rs*16 + 2*w + 1] = aB;
    }
    __syncthreads();

    // -------- phase 1: bias + activation, 2 slots/thread (1024 total) --------
    {
      int s0 = tid*2;
      #pragma unroll
      for (int e = 0; e < 2; ++e) {
        int s = s0 + e;
        int q = (s >> 4) & 3;
        double v = sc[s] + czl[s];
        v = (q == 2) ? tanh(v) : 1.0/(1.0 + exp(-v));
        sc[s] = v;
      }
    }
    __syncthreads();

    // -------- phase 2: cell update (tid < 256; cc in register) --------
    if (tid < 256) {
      int bb = tid >> 4, ul = tid & 15;
      double ig = sc[bb*64 +      ul];
      double fg = sc[bb*64 + 16 + ul];
      double gv = sc[bb*64 + 32 + ul];
      double og = sc[bb*64 + 48 + ul];
      double c2 = fg*cc + ig*gv;
      cc = c2;
      double hv = og*tanh(c2);
      size_t gidx = (size_t)(bG*16 + bb)*512 + nG*16 + ul;
      hbuf[(size_t)((t+1)&1)*65536 + gidx] = hv;
      hs[(size_t)t*65536 + gidx] = (f16)hv;
      if (t == 1023) hlast[gidx] = hv;
    }
    __syncthreads();

    if (tid == 0 && t < 1023) {
      __threadfence();
      __hip_atomic_fetch_add(mc, 1u, __ATOMIC_RELEASE, __HIP_MEMORY_SCOPE_AGENT);
    }
  }
}

// ---------------- K3: bulk output projection (f16 MFMA; 0.108 threshold) ----------------
__global__ __launch_bounds__(256) void k3(const f16* __restrict__ hsA, const f16* __restrict__ wof,
                                          const float* __restrict__ bout, float* __restrict__ out)
{
  int wg = blockIdx.x;                    // 2048 = 1024 Mtiles x 2 Nhalves
  int mt = wg >> 1, nh = wg & 1;
  int tid = threadIdx.x, wid = tid>>6, lane = tid&63;
  int l15 = lane&15, lk = lane>>4;
  int mrow = mt*128 + wid*32;
  f32x4 acc[2][8];
  #pragma unroll
  for (int mf=0;mf<2;mf++)
  #pragma unroll
  for (int nf=0;nf<8;nf++) acc[mf][nf] = (f32x4){0.f,0.f,0.f,0.f};
  int aoff0 = (mrow + l15)*512 + lk*8;
  int boff[8]; float bo[8];
  #pragma unroll
  for (int nf=0;nf<8;nf++){
    int o = nh*128 + nf*16 + l15;
    boff[nf] = o*512 + lk*8;
    bo[nf] = bout[o];
  }
  #pragma unroll 2
  for (int kb=0;kb<16;kb++){
    int k0 = kb*32;
    f16x8 a0 = *(const f16x8*)&hsA[(size_t)aoff0 + k0];
    f16x8 a1 = *(const f16x8*)&hsA[(size_t)aoff0 + 16*512 + k0];
    f16x8 bf[8];
    #pragma unroll
    for (int nf=0;nf<8;nf++) bf[nf] = *(const f16x8*)&wof[boff[nf]+k0];
    #pragma unroll
    for (int nf=0;nf<8;nf++){
      acc[0][nf] = MFMA16(a0, bf[nf], acc[0][nf]);
      acc[1][nf] = MFMA16(a1, bf[nf], acc[1][nf]);
    }
  }
  #pragma unroll
  for (int mf=0;mf<2;mf++)
  #pragma unroll
  for (int nf=0;nf<8;nf++)
  #pragma unroll
  for (int r=0;r<4;r++){
    int m = mrow + mf*16 + lk*4 + r;
    int b = m & 127, tt = m >> 7;
    int o = nh*128 + nf*16 + l15;
    out[((size_t)b*1024 + tt)*256 + o] = acc[mf][nf][r] + bo[nf];
  }
}

// ---------------- K3b: t=1023 logits from f64 h (f64 dot) ----------------
__global__ void k3b(const double* __restrict__ hlast, const float* __restrict__ Wout,
                    const float* __restrict__ bout, float* __restrict__ out)
{
  int b = blockIdx.x, o = threadIdx.x;
  const double* hr = hlast + b*512;
  const float* wr = Wout + o*512;
  double s = (double)bout[o];
  for (int k=0;k<512;k++) s += hr[k] * (double)wr[k];
  out[((size_t)b*1024 + 1023)*256 + o] = (float)s;
}

// ---------------- K4a: categorical (threefry-partitionable, XOR-fold) ----------------
// VERIFIED round 7: per-element u64 counter n; block (x0=0, x1=n);
// 32-bit draw = y0 ^ y1.
__global__ void k4a(const float* __restrict__ outr, float* __restrict__ dout,
                    uint32_t fk0, uint32_t fk1)
{
  int b = blockIdx.x, o = threadIdx.x;
  float logit = outr[((size_t)b*1024 + 1023)*256 + o];
  uint32_t n = (uint32_t)(b*256 + o);
  uint32_t y0, y1;
  tf2x32(fk0, fk1, 0u, n, &y0, &y1);
  uint32_t bits = y0 ^ y1;
  float fl = __uint_as_float((bits>>9) | 0x3f800000u) - 1.0f;
  const float TINY = 1.17549435e-38f;
  float u = fmaxf(fl + TINY, TINY);
  float gum = -logf(-logf(u));
  float score = logit + gum;
  __shared__ float sv[256]; __shared__ int si[256];
  sv[o] = score; si[o] = o; __syncthreads();
  for (int s=128;s>0;s>>=1){
    if (o < s){
      float v2 = sv[o+s]; int i2 = si[o+s];
      if (v2 > sv[o] || (v2 == sv[o] && i2 < si[o])) { sv[o] = v2; si[o] = i2; }
    }
    __syncthreads();
  }
  int widx = si[0];
  dout[(size_t)33554433 + (size_t)b*262144 + 1023*256 + o] = (o == widx) ? 1.0f : 0.0f;
  if (b==0 && o==0) dout[33554432] = 0.0f;
}

// ---------------- K4b: sampled_output[:, :1023] = seq_input[:, 1:] ----------------
__global__ void k4b(const float* __restrict__ seq, float* __restrict__ dout)
{
  int gi = blockIdx.x*256 + threadIdx.x;
  int b = gi / 65472;
  int rr = (gi % 65472)*4;
  f32x4 v = *(const f32x4*)&seq[(size_t)b*262144 + 256 + rr];
  size_t d = (size_t)33554433 + (size_t)b*262144 + rr;
  dout[d]   = v.x; dout[d+1] = v.y; dout[d+2] = v.z; dout[d+3] = v.w;
}

extern "C" void kernel_launch(void* const* d_in, const int* in_sizes, int n_in,
                              void* d_out, int out_size, void* d_ws, size_t ws_size,
                              hipStream_t stream) {
  const float* z    = (const float*)d_in[0];
  const float* seq  = (const float*)d_in[1];
  const float* Wemb = (const float*)d_in[2];
  const float* bemb = (const float*)d_in[3];
  const float* Wih  = (const float*)d_in[4];
  const float* Whh  = (const float*)d_in[5];
  const float* bih  = (const float*)d_in[6];
  const float* bhh  = (const float*)d_in[7];
  const float* Wout = (const float*)d_in[8];
  const float* bout = (const float*)d_in[9];
  float* out = (float*)d_out;
  char* ws = (char*)d_ws;

  double* czb   = (double*)(ws + WS_CZB);
  double* c0    = (double*)(ws + WS_C0);
  double* hbuf  = (double*)(ws + WS_HBUF);
  double* hlast = (double*)(ws + WS_HLAST);
  f16*    wof   = (f16*)(ws + WS_WOF);
  unsigned int* ctr = (unsigned int*)(ws + WS_CTR);

  // hs (f16, 128 MiB) aliased into the sampled_output half of d_out;
  // consumed by k3 before k4a/k4b overwrite it.
  f16* hs = (f16*)(out + 33554432);

  uint32_t fk0, fk1;
  tf2x32(0u, 0u, 0u, 1234u, &fk0, &fk1);   // fold_in(key(0), 1234)

  hipMemsetAsync(ws + WS_CTR, 0, 512, stream);
  k1a<<<1536, 256, 0, stream>>>(z, Wemb, bemb, Wih, bih, bhh, hbuf, c0, czb);
  k1b<<<128, 256, 0, stream>>>(Wout, wof);
  k2t<<<256, 512, 0, stream>>>(seq, Wih, Whh, czb, c0, hbuf, hs, hlast, ctr);
  k3<<<2048, 256, 0, stream>>>(hs, wof, bout, out);
  k3b<<<128, 256, 0, stream>>>(hlast, Wout, bout, out);
  k4a<<<128, 256, 0, stream>>>(out, out, fk0, fk1);
  k4b<<<32736, 256, 0, stream>>>(seq, out);
}

// Round 12
// 38845.740 us; speedup vs baseline: 10.6594x; 10.6594x over previous
//
#include <hip/hip_runtime.h>
#include <stdint.h>
#include <stddef.h>

typedef _Float16 f16;
typedef __attribute__((ext_vector_type(8))) _Float16 f16x8;
typedef __attribute__((ext_vector_type(4))) float f32x4;
typedef __attribute__((ext_vector_type(2))) double f64x2;

#define MFMA16(A,B,C) __builtin_amdgcn_mfma_f32_16x16x32_f16((A),(B),(C),0,0,0)

// B=128, T=1024, FEAT=256, HID=512, GATES=2048, K=768 (256 seq + 512 h)
// f64 recurrence (ref=np is f64-grade; step-error gain ~1e5).
// ROOT CAUSE of r9-r11: __launch_bounds__(512,2) = 2 blocks/CU = 4 waves/SIMD
// -> VGPR cap 128. 96 f64 weights (192 VGPR) could never be resident: r9/r10
// remat'd weight loads in-loop (39.7ms, L2-stream-bound); r11's acc arrays
// spilled to scratch (414ms, 1.1TB HBM). Fix: launch_bounds(512,1) -> 1 WG/CU
// (what we run anyway) -> 256-VGPR budget; weights fit. Structure = r10 k2s.

// ---------------- workspace byte offsets ----------------
#define WS_CZB   0            // f64[128][512][4]  = 2 MiB
#define WS_C0    2097152      // f64[128*512]      = 512 KiB
#define WS_HBUF  2621440      // f64[2][128][512]  = 1 MiB (parity, batch, unit)
#define WS_HLAST 3670016      // f64[128*512]      = 512 KiB
#define WS_WOF   4194304      // f16[256*512]      = 256 KiB
#define WS_CTR   4456448      // u32 counters (8 groups x 16 stride)

// JAX threefry2x32 (20 rounds), host+device
__host__ __device__ __forceinline__ void tf2x32(uint32_t k0,uint32_t k1,uint32_t x0,uint32_t x1,
                                                uint32_t* o0,uint32_t* o1){
  uint32_t ks2 = k0 ^ k1 ^ 0x1BD11BDAu;
  uint32_t a = x0 + k0, b = x1 + k1;
  #define TF_R(rot) { a += b; b = (b<<(rot))|(b>>(32-(rot))); b ^= a; }
  TF_R(13) TF_R(15) TF_R(26) TF_R(6)  a += k1;  b += ks2 + 1u;
  TF_R(17) TF_R(29) TF_R(16) TF_R(24) a += ks2; b += k0  + 2u;
  TF_R(13) TF_R(15) TF_R(26) TF_R(6)  a += k0;  b += k1  + 3u;
  TF_R(17) TF_R(29) TF_R(16) TF_R(24) a += k1;  b += ks2 + 4u;
  TF_R(13) TF_R(15) TF_R(26) TF_R(6)  a += ks2; b += k0  + 5u;
  #undef TF_R
  *o0 = a; *o1 = b;
}

// ---------------- K1a: embed h0/c0 + Czb (z-part + biases), all f64 ----------------
__global__ void k1a(const float* __restrict__ z, const float* __restrict__ Wemb,
                    const float* __restrict__ bemb, const float* __restrict__ Wih,
                    const float* __restrict__ bih, const float* __restrict__ bhh,
                    double* __restrict__ h0, double* __restrict__ c0,
                    double* __restrict__ czb)
{
  int gi = blockIdx.x*256 + threadIdx.x;       // 128*3072 threads
  int b = gi / 3072, j = gi % 3072;
  const float* zr = z + b*256;
  if (j < 1024) {
    const float* wr = Wemb + j*256;
    double s = (double)bemb[j];
    for (int k=0;k<256;k++) s += (double)zr[k] * (double)wr[k];
    double v = tanh(s);
    if (j < 512) h0[b*512 + j] = v;            // hbuf parity 0, [b][u]
    else         c0[b*512 + (j-512)] = v;
  } else {
    int g = j - 1024;
    const float* wr = Wih + g*512 + 256;       // z-columns of W_ih
    double s = (double)bih[g] + (double)bhh[g];
    for (int k=0;k<256;k++) s += (double)zr[k] * (double)wr[k];
    int q = g >> 9, u = g & 511;
    czb[(b*512 + u)*4 + q] = s;
  }
}

// ---------------- K1b: W_out -> f16 for the bulk projection ----------------
__global__ void k1b(const float* __restrict__ Wout, f16* __restrict__ wof)
{
  int e0 = (blockIdx.x*256 + threadIdx.x)*4;   // 128 blocks
  #pragma unroll
  for (int j=0;j<4;j++) wof[e0+j] = (f16)Wout[e0+j];
}

// ---------------- K2: persistent f64 LSTM, weights resident (256-VGPR budget) ----------------
// 256 WGs x 512 thr (1 WG/CU). WG = bG (16 batches) x nG (16 units = 64 gate rows).
// lane = kc*4 + rs; wave w owns units {2w, 2w+1}. Lane holds 2 rows' K-chunks
// as f64 in VGPRs (96 f64 = 192 VGPR), asm-pinned. Per bb: fused seq(32 FMA)
// + h(64 FMA) into 4 chains, ONE 4-round shfl butterfly. x/h staged to
// XOR-swizzled LDS; per-bG 32-WG monotonic counter barrier.
__global__ __launch_bounds__(512, 1) void k2u(
    const float* __restrict__ seq, const float* __restrict__ Wih,
    const float* __restrict__ Whh,
    const double* __restrict__ czbv, const double* __restrict__ c0v,
    double* __restrict__ hbuf, f16* __restrict__ hs, double* __restrict__ hlast,
    unsigned int* __restrict__ ctr)
{
  __shared__ double xl[4096];      // 32KB  x_t  [bb][256]
  __shared__ double hl[8192];      // 64KB  h_t  [bb][512]
  __shared__ double sc[1024];      // 8KB   gate sums [bb][q][ul]
  __shared__ double czl[1024];     // 8KB   biases, same layout

  const int tid = threadIdx.x;
  const int bid = blockIdx.x;
  const int bG = bid & 7, nG = bid >> 3;
  const int w = tid >> 6, lane = tid & 63;
  const int kc = lane >> 2, rs = lane & 3;
  const int XR = (kc & 7) << 4;                        // read-side swizzle const

  // physical gate rows for this lane's two units
  const int uA = nG*16 + 2*w;
  const size_t rA = (size_t)(rs*512 + uA);
  const size_t rB = rA + 1;

  // ---- one-time: weights -> f64 registers, asm-pinned (never reloaded) ----
  double wsA[16], wsB[16], whA[32], whB[32];
  {
    const float* pA = Wih + rA*512 + kc*16;
    const float* pB = Wih + rB*512 + kc*16;
    #pragma unroll
    for (int j=0;j<16;j++){ wsA[j] = (double)pA[j]; wsB[j] = (double)pB[j]; }
    const float* qA = Whh + rA*512 + kc*32;
    const float* qB = Whh + rB*512 + kc*32;
    #pragma unroll
    for (int j=0;j<32;j++){ whA[j] = (double)qA[j]; whB[j] = (double)qB[j]; }
    #pragma unroll
    for (int j=0;j<16;j++){ asm volatile("" : "+v"(wsA[j])); asm volatile("" : "+v"(wsB[j])); }
    #pragma unroll
    for (int j=0;j<32;j++){ asm volatile("" : "+v"(whA[j])); asm volatile("" : "+v"(whB[j])); }
  }

  // ---- one-time: biases into LDS (czl[bb*64 + q*16 + ul]) ----
  for (int s = tid; s < 1024; s += 512) {
    int bb = s >> 6, q = (s >> 4) & 3, ul = s & 15;
    czl[s] = czbv[(size_t)((bG*16+bb)*512 + nG*16 + ul)*4 + q];
  }

  // elementwise ownership (tid < 256): cc in register for all 1024 steps
  double cc = 0.0;
  if (tid < 256) cc = c0v[(size_t)(bG*16 + (tid>>4))*512 + nG*16 + (tid&15)];

  // staging geometry
  const int lane5 = tid & 31;
  const int srow  = tid >> 5;        // 0..15 (batch row for staging)
  const int xchk  = lane5 >> 1;      // x: 128B chunk 0..15 (2 threads/chunk)
  const int xhalf = lane5 & 1;       // which 4-pair half
  const int xswz  = xchk & 7;
  const int hswz  = (lane5 >> 1) & 7;  // h: chunk = lane5, swz = (chunk>>1)&7

  unsigned int* mc = &ctr[bG*16];
  __syncthreads();

  for (int t = 0; t < 1024; ++t) {
    // -------- stage x_t: f32 -> f64, XOR-swizzled (8 elems/thread) --------
    {
      const float* xsrc = seq + (size_t)(bG*16 + srow)*262144 + (size_t)t*256 + lane5*8;
      f32x4 v0 = *(const f32x4*)xsrc;
      f32x4 v1 = *(const f32x4*)(xsrc + 4);
      char* wbase = (char*)xl + srow*2048 + xchk*128;
      f64x2 pr0 = {(double)v0.x, (double)v0.y};
      f64x2 pr1 = {(double)v0.z, (double)v0.w};
      f64x2 pr2 = {(double)v1.x, (double)v1.y};
      f64x2 pr3 = {(double)v1.z, (double)v1.w};
      *(f64x2*)(wbase + (((xhalf*4 + 0) ^ xswz) << 4)) = pr0;
      *(f64x2*)(wbase + (((xhalf*4 + 1) ^ xswz) << 4)) = pr1;
      *(f64x2*)(wbase + (((xhalf*4 + 2) ^ xswz) << 4)) = pr2;
      *(f64x2*)(wbase + (((xhalf*4 + 3) ^ xswz) << 4)) = pr3;
    }

    // -------- wait: all 32 same-bG WGs published h_t --------
    if (t) {
      if (tid == 0) {
        unsigned tgt = 32u * (unsigned)t;
        while (__hip_atomic_load(mc, __ATOMIC_RELAXED, __HIP_MEMORY_SCOPE_AGENT) < tgt)
          __builtin_amdgcn_s_sleep(1);
        (void)__hip_atomic_load(mc, __ATOMIC_ACQUIRE, __HIP_MEMORY_SCOPE_AGENT);
      }
    }
    __syncthreads();

    // -------- stage h_t: global f64 -> LDS, XOR-swizzled (16 elems/thread) --------
    {
      const double* hsrc = hbuf + (size_t)(t & 1)*65536 + (size_t)(bG*16 + srow)*512 + lane5*16;
      char* wbase = (char*)hl + srow*4096 + lane5*128;
      #pragma unroll
      for (int g = 0; g < 8; ++g) {
        f64x2 hv = *(const f64x2*)(hsrc + 2*g);
        *(f64x2*)(wbase + ((g ^ hswz) << 4)) = hv;
      }
    }
    __syncthreads();

    // -------- fused seq+h partials per bb; ONE butterfly per bb --------
    for (int bb = 0; bb < 16; ++bb) {
      const char* xb  = (const char*)xl + bb*2048 + kc*128;
      const char* hb2 = (const char*)hl + bb*4096 + kc*256;
      double aA0=0., aA1=0., aB0=0., aB1=0.;
      #pragma unroll
      for (int j2 = 0; j2 < 8; ++j2) {
        f64x2 xv = *(const f64x2*)(xb + ((j2*16) ^ XR));
        aA0 += wsA[2*j2]   * xv.x;
        aA1 += wsA[2*j2+1] * xv.y;
        aB0 += wsB[2*j2]   * xv.x;
        aB1 += wsB[2*j2+1] * xv.y;
      }
      #pragma unroll
      for (int j2 = 0; j2 < 16; ++j2) {
        f64x2 hv = *(const f64x2*)(hb2 + ((j2*16) ^ XR));
        aA0 += whA[2*j2]   * hv.x;
        aA1 += whA[2*j2+1] * hv.y;
        aB0 += whB[2*j2]   * hv.x;
        aB1 += whB[2*j2+1] * hv.y;
      }
      double aA = aA0 + aA1, aB = aB0 + aB1;
      #pragma unroll
      for (int off = 4; off < 64; off <<= 1) {
        aA += __shfl_xor(aA, off, 64);
        aB += __shfl_xor(aB, off, 64);
      }
      if (kc == 0) sc[bb*64 + rs*16 + 2*w]     = aA;
      if (kc == 1) sc[bb*64 + rs*16 + 2*w + 1] = aB;
    }
    __syncthreads();

    // -------- phase 1: bias + activation, 2 slots/thread (1024 total) --------
    {
      int s0 = tid*2;
      #pragma unroll
      for (int e = 0; e < 2; ++e) {
        int s = s0 + e;
        int q = (s >> 4) & 3;
        double v = sc[s] + czl[s];
        v = (q == 2) ? tanh(v) : 1.0/(1.0 + exp(-v));
        sc[s] = v;
      }
    }
    __syncthreads();

    // -------- phase 2: cell update (tid < 256; cc in register) --------
    if (tid < 256) {
      int bb = tid >> 4, ul = tid & 15;
      double ig = sc[bb*64 +      ul];
      double fg = sc[bb*64 + 16 + ul];
      double gv = sc[bb*64 + 32 + ul];
      double og = sc[bb*64 + 48 + ul];
      double c2 = fg*cc + ig*gv;
      cc = c2;
      double hv = og*tanh(c2);
      size_t gidx = (size_t)(bG*16 + bb)*512 + nG*16 + ul;
      hbuf[(size_t)((t+1)&1)*65536 + gidx] = hv;
      hs[(size_t)t*65536 + gidx] = (f16)hv;
      if (t == 1023) hlast[gidx] = hv;
    }
    __syncthreads();

    if (tid == 0 && t < 1023) {
      __threadfence();
      __hip_atomic_fetch_add(mc, 1u, __ATOMIC_RELEASE, __HIP_MEMORY_SCOPE_AGENT);
    }
  }
}

// ---------------- K3: bulk output projection (f16 MFMA; 0.108 threshold) ----------------
__global__ __launch_bounds__(256) void k3(const f16* __restrict__ hsA, const f16* __restrict__ wof,
                                          const float* __restrict__ bout, float* __restrict__ out)
{
  int wg = blockIdx.x;                    // 2048 = 1024 Mtiles x 2 Nhalves
  int mt = wg >> 1, nh = wg & 1;
  int tid = threadIdx.x, wid = tid>>6, lane = tid&63;
  int l15 = lane&15, lk = lane>>4;
  int mrow = mt*128 + wid*32;
  f32x4 acc[2][8];
  #pragma unroll
  for (int mf=0;mf<2;mf++)
  #pragma unroll
  for (int nf=0;nf<8;nf++) acc[mf][nf] = (f32x4){0.f,0.f,0.f,0.f};
  int aoff0 = (mrow + l15)*512 + lk*8;
  int boff[8]; float bo[8];
  #pragma unroll
  for (int nf=0;nf<8;nf++){
    int o = nh*128 + nf*16 + l15;
    boff[nf] = o*512 + lk*8;
    bo[nf] = bout[o];
  }
  #pragma unroll 2
  for (int kb=0;kb<16;kb++){
    int k0 = kb*32;
    f16x8 a0 = *(const f16x8*)&hsA[(size_t)aoff0 + k0];
    f16x8 a1 = *(const f16x8*)&hsA[(size_t)aoff0 + 16*512 + k0];
    f16x8 bf[8];
    #pragma unroll
    for (int nf=0;nf<8;nf++) bf[nf] = *(const f16x8*)&wof[boff[nf]+k0];
    #pragma unroll
    for (int nf=0;nf<8;nf++){
      acc[0][nf] = MFMA16(a0, bf[nf], acc[0][nf]);
      acc[1][nf] = MFMA16(a1, bf[nf], acc[1][nf]);
    }
  }
  #pragma unroll
  for (int mf=0;mf<2;mf++)
  #pragma unroll
  for (int nf=0;nf<8;nf++)
  #pragma unroll
  for (int r=0;r<4;r++){
    int m = mrow + mf*16 + lk*4 + r;
    int b = m & 127, tt = m >> 7;
    int o = nh*128 + nf*16 + l15;
    out[((size_t)b*1024 + tt)*256 + o] = acc[mf][nf][r] + bo[nf];
  }
}

// ---------------- K3b: t=1023 logits from f64 h (f64 dot) ----------------
__global__ void k3b(const double* __restrict__ hlast, const float* __restrict__ Wout,
                    const float* __restrict__ bout, float* __restrict__ out)
{
  int b = blockIdx.x, o = threadIdx.x;
  const double* hr = hlast + b*512;
  const float* wr = Wout + o*512;
  double s = (double)bout[o];
  for (int k=0;k<512;k++) s += hr[k] * (double)wr[k];
  out[((size_t)b*1024 + 1023)*256 + o] = (float)s;
}

// ---------------- K4a: categorical (threefry-partitionable, XOR-fold) ----------------
// VERIFIED round 7: per-element u64 counter n; block (x0=0, x1=n);
// 32-bit draw = y0 ^ y1.
__global__ void k4a(const float* __restrict__ outr, float* __restrict__ dout,
                    uint32_t fk0, uint32_t fk1)
{
  int b = blockIdx.x, o = threadIdx.x;
  float logit = outr[((size_t)b*1024 + 1023)*256 + o];
  uint32_t n = (uint32_t)(b*256 + o);
  uint32_t y0, y1;
  tf2x32(fk0, fk1, 0u, n, &y0, &y1);
  uint32_t bits = y0 ^ y1;
  float fl = __uint_as_float((bits>>9) | 0x3f800000u) - 1.0f;
  const float TINY = 1.17549435e-38f;
  float u = fmaxf(fl + TINY, TINY);
  float gum = -logf(-logf(u));
  float score = logit + gum;
  __shared__ float sv[256]; __shared__ int si[256];
  sv[o] = score; si[o] = o; __syncthreads();
  for (int s=128;s>0;s>>=1){
    if (o < s){
      float v2 = sv[o+s]; int i2 = si[o+s];
      if (v2 > sv[o] || (v2 == sv[o] && i2 < si[o])) { sv[o] = v2; si[o] = i2; }
    }
    __syncthreads();
  }
  int widx = si[0];
  dout[(size_t)33554433 + (size_t)b*262144 + 1023*256 + o] = (o == widx) ? 1.0f : 0.0f;
  if (b==0 && o==0) dout[33554432] = 0.0f;
}

// ---------------- K4b: sampled_output[:, :1023] = seq_input[:, 1:] ----------------
__global__ void k4b(const float* __restrict__ seq, float* __restrict__ dout)
{
  int gi = blockIdx.x*256 + threadIdx.x;
  int b = gi / 65472;
  int rr = (gi % 65472)*4;
  f32x4 v = *(const f32x4*)&seq[(size_t)b*262144 + 256 + rr];
  size_t d = (size_t)33554433 + (size_t)b*262144 + rr;
  dout[d]   = v.x; dout[d+1] = v.y; dout[d+2] = v.z; dout[d+3] = v.w;
}

extern "C" void kernel_launch(void* const* d_in, const int* in_sizes, int n_in,
                              void* d_out, int out_size, void* d_ws, size_t ws_size,
                              hipStream_t stream) {
  const float* z    = (const float*)d_in[0];
  const float* seq  = (const float*)d_in[1];
  const float* Wemb = (const float*)d_in[2];
  const float* bemb = (const float*)d_in[3];
  const float* Wih  = (const float*)d_in[4];
  const float* Whh  = (const float*)d_in[5];
  const float* bih  = (const float*)d_in[6];
  const float* bhh  = (const float*)d_in[7];
  const float* Wout = (const float*)d_in[8];
  const float* bout = (const float*)d_in[9];
  float* out = (float*)d_out;
  char* ws = (char*)d_ws;

  double* czb   = (double*)(ws + WS_CZB);
  double* c0    = (double*)(ws + WS_C0);
  double* hbuf  = (double*)(ws + WS_HBUF);
  double* hlast = (double*)(ws + WS_HLAST);
  f16*    wof   = (f16*)(ws + WS_WOF);
  unsigned int* ctr = (unsigned int*)(ws + WS_CTR);

  // hs (f16, 128 MiB) aliased into the sampled_output half of d_out;
  // consumed by k3 before k4a/k4b overwrite it.
  f16* hs = (f16*)(out + 33554432);

  uint32_t fk0, fk1;
  tf2x32(0u, 0u, 0u, 1234u, &fk0, &fk1);   // fold_in(key(0), 1234)

  hipMemsetAsync(ws + WS_CTR, 0, 512, stream);
  k1a<<<1536, 256, 0, stream>>>(z, Wemb, bemb, Wih, bih, bhh, hbuf, c0, czb);
  k1b<<<128, 256, 0, stream>>>(Wout, wof);
  k2u<<<256, 512, 0, stream>>>(seq, Wih, Whh, czb, c0, hbuf, hs, hlast, ctr);
  k3<<<2048, 256, 0, stream>>>(hs, wof, bout, out);
  k3b<<<128, 256, 0, stream>>>(hlast, Wout, bout, out);
  k4a<<<128, 256, 0, stream>>>(out, out, fk0, fk1);
  k4b<<<32736, 256, 0, stream>>>(seq, out);
}